// Round 5
// baseline (672.318 us; speedup 1.0000x reference)
//
#include <hip/hip_runtime.h>

#define THETA_DIM 11

typedef float v2f __attribute__((ext_vector_type(2)));

__device__ __forceinline__ v2f v2(float s) { return (v2f){s, s}; }

// Pair exchange within a quad: quad_perm:[1,0,3,2] -> ctrl 0xB1.
// Full-rate VALU, no LDS; compiler inserts required hazard wait-states.
__device__ __forceinline__ float dpp_xor1(float v) {
  return __builtin_bit_cast(float,
    __builtin_amdgcn_update_dpp(0, __builtin_bit_cast(int, v), 0xB1, 0xF, 0xF, true));
}

// Layout: 2 lanes per chain (lane h in {0,1} holds softmax components
// {2h,2h+1} as packed v2f) x 2 independent chains per lane (A: base+cc,
// B: base+32+cc). 64 chains/wave, 128 waves.
//   - k=2 halves the replicated chain-wide scalar work vs k=4 and needs only
//     ONE dpp stage per reduction: per-chain issue ~75 cy/step.
//   - the second chain's instructions fill the first chain's dependency-
//     latency bubbles (proven in the round-1 2-chain kernel: 86% busy).
// Per 2-step window: issue ~150 cy vs dep path ~130-185 cy -> ~85-95 cy/step.
__global__ void __launch_bounds__(64, 1)
bh_kernel(const float* __restrict__ theta, const float* __restrict__ eps,
          float* __restrict__ out, int Tn) {
  const int tid = threadIdx.x;
  const int cc = tid >> 1;               // chain column 0..31
  const int h  = tid & 1;                // component pair: {2h, 2h+1}
  const int base = blockIdx.x * 64;
  const int bA = base + cc;
  const int bB = base + 32 + cc;

  const float L2E = 1.4426950408889634f;

  // ---- chain A constants ----
  const float* tha = theta + (size_t)bA * THETA_DIM;
  const float beta_a = tha[0];
  const v2f ga  = {tha[1 + 2 * h], tha[2 + 2 * h]};
  const v2f bba = {tha[5 + 2 * h], tha[6 + 2 * h]};
  const float sig_a = tha[9];
  const float Ra    = 1.0f + tha[10];
  const float invRa = 1.0f / Ra;
  const float bl2e_a  = beta_a * L2E;
  const float bl2eR_a = bl2e_a * Ra;
  const float sR_a    = sig_a * invRa;
  const v2f gRa = ga * v2(invRa), bRa = bba * v2(invRa);
  const v2f nRa = v2(-Ra);

  // ---- chain B constants ----
  const float* thb = theta + (size_t)bB * THETA_DIM;
  const float beta_b = thb[0];
  const v2f gb  = {thb[1 + 2 * h], thb[2 + 2 * h]};
  const v2f bbb = {thb[5 + 2 * h], thb[6 + 2 * h]};
  const float sig_b = thb[9];
  const float Rb    = 1.0f + thb[10];
  const float invRb = 1.0f / Rb;
  const float bl2e_b  = beta_b * L2E;
  const float bl2eR_b = bl2e_b * Rb;
  const float sR_b    = sig_b * invRb;
  const v2f gRb = gb * v2(invRb), bRb = bbb * v2(invRb);
  const v2f nRb = v2(-Rb);

  // ---- chain A state ----
  float x1a = 0.f, x2a = 0.f, m1a = 0.f;
  v2f qa = bba, ca = bRa;
  float qmaxa, qmina;
  {
    float mx = fmaxf(qa.x, qa.y), mn = fminf(qa.x, qa.y);
    qmaxa = fmaxf(mx, dpp_xor1(mx));
    qmina = fminf(mn, dpp_xor1(mn));
  }
  // ---- chain B state ----
  float x1b = 0.f, x2b = 0.f, m1b = 0.f;
  v2f qb = bbb, cb = bRb;
  float qmaxb, qminb;
  {
    float mx = fmaxf(qb.x, qb.y), mn = fminf(qb.x, qb.y);
    qmaxb = fmaxf(mx, dpp_xor1(mx));
    qminb = fminf(mn, dpp_xor1(mn));
  }

  // Fused double step: both chains, statements interleaved.
  auto step2 = [&](float ea, float eb, float& xa_out, float& xb_out) {
    // ---- on-path ----
    const float Aa = fmaf(bl2e_a, x1a, -m1a);
    const float Ab = fmaf(bl2e_b, x1b, -m1b);
    const float ma = fmaxf(Aa * qmaxa, Aa * qmina);
    const float mb = fmaxf(Ab * qmaxb, Ab * qminb);
    const v2f eoa = __builtin_elementwise_fma(v2(Aa), qa, v2(-ma));
    const v2f eob = __builtin_elementwise_fma(v2(Ab), qb, v2(-mb));
    const v2f pa = {__builtin_amdgcn_exp2f(eoa.x), __builtin_amdgcn_exp2f(eoa.y)};
    const v2f pb = {__builtin_amdgcn_exp2f(eob.x), __builtin_amdgcn_exp2f(eob.y)};
    const v2f pca = pa * ca;
    const v2f pcb = pb * cb;
    const float sda = pa.x + pa.y,   sna = pca.x + pca.y;
    const float sdb = pb.x + pb.y,   snb = pcb.x + pcb.y;
    const float dena = sda + dpp_xor1(sda);
    const float denb = sdb + dpp_xor1(sdb);
    const float numa = sna + dpp_xor1(sna);
    const float numb = snb + dpp_xor1(snb);
    // ---- off-path: next-step q and its max/min from pre-shift state ----
    const v2f wa  = __builtin_elementwise_fma(ga, v2(x2a), bba);
    const v2f wb  = __builtin_elementwise_fma(gb, v2(x2b), bbb);
    const v2f qna = __builtin_elementwise_fma(nRa, v2(x1a), wa);
    const v2f qnb = __builtin_elementwise_fma(nRb, v2(x1b), wb);
    const float mxa = fmaxf(qna.x, qna.y), mna = fminf(qna.x, qna.y);
    const float mxb = fmaxf(qnb.x, qnb.y), mnb = fminf(qnb.x, qnb.y);
    const float qmaxna = fmaxf(mxa, dpp_xor1(mxa));
    const float qminna = fminf(mna, dpp_xor1(mna));
    const float qmaxnb = fmaxf(mxb, dpp_xor1(mxb));
    const float qminnb = fminf(mnb, dpp_xor1(mnb));
    const float m1na = bl2eR_a * x1a;
    const float m1nb = bl2eR_b * x1b;
    // ---- on-path finish ----
    const float xa = fmaf(numa, __builtin_amdgcn_rcpf(dena), ea * sR_a);
    const float xb = fmaf(numb, __builtin_amdgcn_rcpf(denb), eb * sR_b);
    // ---- shift ----
    x2a = x1a; x1a = xa;
    x2b = x1b; x1b = xb;
    qa = qna; qmaxa = qmaxna; qmina = qminna; m1a = m1na;
    qb = qnb; qmaxb = qmaxnb; qminb = qminnb; m1b = m1nb;
    ca = __builtin_elementwise_fma(gRa, v2(xa), bRa);
    cb = __builtin_elementwise_fma(gRb, v2(xb), bRb);
    xa_out = xa; xb_out = xb;
  };

  const float* epa = eps + (size_t)bA * Tn;   // both pair lanes read same row
  const float* epb = eps + (size_t)bB * Tn;
  float* opa = out + (size_t)bA * Tn;
  float* opb = out + (size_t)bB * Tn;
  const bool writer = (h == 0);

  // eps register pipeline: 16-float blocks per chain, 1 block ahead
  // (~16 steps ~ 1400+ cy of cover vs ~900 cy HBM latency).
  float4 curA[4], curB[4], nxtA[4], nxtB[4];
  #pragma unroll
  for (int i = 0; i < 4; ++i) {
    curA[i] = *(const float4*)(epa + i * 4);
    curB[i] = *(const float4*)(epb + i * 4);
  }

  const int NB = Tn / 16;
  int t0 = 0;
  for (int blk = 0; blk < NB; ++blk) {
    int tl = t0 + 16;
    if (tl > Tn - 16) tl = Tn - 16;
    #pragma unroll
    for (int i = 0; i < 4; ++i) {
      nxtA[i] = *(const float4*)(epa + tl + i * 4);
      nxtB[i] = *(const float4*)(epb + tl + i * 4);
    }

    #pragma unroll
    for (int i = 0; i < 4; ++i) {
      float4 oA, oB;
      step2(curA[i].x, curB[i].x, oA.x, oB.x);
      step2(curA[i].y, curB[i].y, oA.y, oB.y);
      step2(curA[i].z, curB[i].z, oA.z, oB.z);
      step2(curA[i].w, curB[i].w, oA.w, oB.w);
      if (writer) {
        *(float4*)(opa + t0 + i * 4) = oA;   // one lane per chain stores
        *(float4*)(opb + t0 + i * 4) = oB;
      }
    }

    #pragma unroll
    for (int i = 0; i < 4; ++i) { curA[i] = nxtA[i]; curB[i] = nxtB[i]; }
    t0 += 16;
  }
}

extern "C" void kernel_launch(void* const* d_in, const int* in_sizes, int n_in,
                              void* d_out, int out_size, void* d_ws, size_t ws_size,
                              hipStream_t stream) {
  const float* theta = (const float*)d_in[0];
  const float* eps   = (const float*)d_in[1];
  float* out = (float*)d_out;
  const int B  = in_sizes[0] / THETA_DIM;   // 8192
  const int Tn = in_sizes[1] / B;           // 4096
  const int blocks = B / 64;                // 128 waves: 32 chain-cols x 2 lanes x 2 chains
  bh_kernel<<<blocks, 64, 0, stream>>>(theta, eps, out, Tn);
}